// Round 6
// baseline (604.165 us; speedup 1.0000x reference)
//
#include <hip/hip_runtime.h>

// Problem constants (fixed by reference)
#define BB 256      // batch
#define TT 1024     // time steps
#define HH 32       // hidden
#define NT 512      // 8 waves
#define CH 64       // emb chunk length (steps)

// 8 waves, one barrier per tick. Critical insight: only gh-dots+gates are on
// the h(t)->h(t+1) recurrence path; gi-dots are feed-forward and run one tick
// ahead on separate waves. 2 waves/SIMD hide each other's latency.
//
// Stage schedule at tick tau (all double-buffered by tick parity):
//   wv6 : y1(tau)  [ebuf]            ; y2(tau-1) [v_y1p regs]  -> y2s
//   wv7 : y3(tau-2) [y2s]            -> y3s ; emb refill /64 ; flush /16
//   wv3 : gi layer0 t=tau-3 [y3s]    -> gib[0]
//   wv0 : gh layer0 t=tau-4 [gib[0], h regs] -> h0s
//   wv4 : gi layer1 t=tau-5 [h0s]    -> gib[1]
//   wv1 : gh layer1 t=tau-6 [gib[1]] -> h1s
//   wv5 : gi layer2 t=tau-7 [h1s]    -> gib[2]
//   wv2 : gh layer2 t=tau-8 [gib[2]] -> obuf ring
// Ticks: tau = 0 .. TT+8  (TT+9 total; last tick flushes the tail).

__device__ __forceinline__ float fast_rcp(float x) { return __builtin_amdgcn_rcpf(x); }
__device__ __forceinline__ float sigm(float x)     { return fast_rcp(1.f + __expf(-x)); }
__device__ __forceinline__ float tanh_fast(float x){ float e = __expf(2.f * x); return 1.f - 2.f * fast_rcp(e + 1.f); }
__device__ __forceinline__ float rlane(float v, int k) {
    return __int_as_float(__builtin_amdgcn_readlane(__float_as_int(v), k));
}

__global__ __launch_bounds__(NT, 1) void rnn_fused(
    const int*   __restrict__ xidx,   // [B,T]
    const float* __restrict__ hid,    // [L,B,H]
    const float* __restrict__ emb,    // [38000,H]
    const float* __restrict__ W1, const float* __restrict__ b1,
    const float* __restrict__ W2, const float* __restrict__ b2,
    const float* __restrict__ W3, const float* __restrict__ b3,
    const float* __restrict__ Wih,    // [L,3H,H]
    const float* __restrict__ Whh,    // [L,3H,H]
    const float* __restrict__ bih,    // [L,3H]
    const float* __restrict__ bhh,    // [L,3H]
    float*       __restrict__ out)    // [B*T*H] ++ [L*B*H]
{
    const int b   = blockIdx.x;
    const int tid = threadIdx.x;
    const int wv  = tid >> 6;          // wave id 0..7
    const int ln  = tid & 63;          // lane
    const int lo  = ln & 31;

    __shared__ int idxbuf[TT];                       // 4 KB
    __shared__ alignas(16) float ebuf[2][CH][HH];    // 16 KB emb chunk dbuf
    __shared__ alignas(16) float y2s[2][HH];         // MLP stage streams
    __shared__ alignas(16) float y3s[2][HH];
    __shared__ alignas(16) float h0s[2][HH];         // GRU inter-layer streams
    __shared__ alignas(16) float h1s[2][HH];
    __shared__ alignas(16) float gib[3][2][96];      // gi dot results (parity dbuf)
    __shared__ alignas(16) float obuf[32][HH];       // 4 KB layer-2 output ring

    // ---- preload token ids ----
    for (int t = tid; t < TT; t += NT) idxbuf[t] = xidx[b * TT + t];
    __syncthreads();

    // ---- preload emb chunk 0 (512 float4 tasks over 512 threads) ----
    {
        float4*       edst = reinterpret_cast<float4*>(&ebuf[0][0][0]);
        const float4* esrc = reinterpret_cast<const float4*>(emb);
        const int row = tid >> 3, q = tid & 7;
        edst[row * 8 + q] = esrc[(size_t)idxbuf[row] * 8 + q];
    }

    // ---- per-role weight registers ----
    float wA[32], wB[32];
    float bA = 0.f, bB = 0.f;
    float v_h = 0.f, v_y1p = 0.f;

    if (wv < 3) {                       // gh waves: Whh rows
        const int rA = ln, rB = 64 + lo;
        const float4* pA = reinterpret_cast<const float4*>(Whh + (size_t)(wv * 96 + rA) * HH);
        const float4* pB = reinterpret_cast<const float4*>(Whh + (size_t)(wv * 96 + rB) * HH);
        #pragma unroll
        for (int i = 0; i < 8; ++i) {
            reinterpret_cast<float4*>(wA)[i] = pA[i];
            reinterpret_cast<float4*>(wB)[i] = pB[i];
        }
        bA = bhh[wv * 96 + rA];
        bB = bhh[wv * 96 + rB];
        if (ln < HH) v_h = hid[(size_t)(wv * BB + b) * HH + ln];
    } else if (wv < 6) {                // gi waves: Wih rows
        const int l = wv - 3, rA = ln, rB = 64 + lo;
        const float4* pA = reinterpret_cast<const float4*>(Wih + (size_t)(l * 96 + rA) * HH);
        const float4* pB = reinterpret_cast<const float4*>(Wih + (size_t)(l * 96 + rB) * HH);
        #pragma unroll
        for (int i = 0; i < 8; ++i) {
            reinterpret_cast<float4*>(wA)[i] = pA[i];
            reinterpret_cast<float4*>(wB)[i] = pB[i];
        }
        bA = bih[l * 96 + rA];
        bB = bih[l * 96 + rB];
    } else if (wv == 6) {               // MLP y1 (W1) + y2 (W2)
        const float4* p1 = reinterpret_cast<const float4*>(W1 + (size_t)lo * HH);
        const float4* p2 = reinterpret_cast<const float4*>(W2 + (size_t)lo * HH);
        #pragma unroll
        for (int i = 0; i < 8; ++i) {
            reinterpret_cast<float4*>(wA)[i] = p1[i];
            reinterpret_cast<float4*>(wB)[i] = p2[i];
        }
        bA = b1[lo];
        bB = b2[lo];
    } else {                            // wv7: y3 (W3) + utilities
        const float4* p3 = reinterpret_cast<const float4*>(W3 + (size_t)lo * HH);
        #pragma unroll
        for (int i = 0; i < 8; ++i) reinterpret_cast<float4*>(wA)[i] = p3[i];
        bA = b3[lo];
    }
    __syncthreads();

    float* const out_seq = out + (size_t)b * TT * HH;
    float* const out_hf  = out + (size_t)BB * TT * HH;

    for (int tau = 0; tau < TT + 9; ++tau) {
        const int cur = tau & 1, prv = cur ^ 1;

        if (wv < 3) {
            // ================= gh waves: recurrence critical path =================
            const int t = tau - 4 - 2 * wv;
            if (t >= 0 && t < TT) {
                // issue gi reads first; latency hides under the register dot loop
                const float giA = gib[wv][prv][ln];
                const float giB = gib[wv][prv][64 + lo];
                float a0 = bA, a1 = 0.f, c0 = bB, c1 = 0.f;
                #pragma unroll
                for (int k = 0; k < 32; k += 2) {
                    const float h0 = rlane(v_h, k), h1 = rlane(v_h, k + 1);
                    a0 = fmaf(wA[k],     h0, a0);
                    a1 = fmaf(wA[k + 1], h1, a1);
                    c0 = fmaf(wB[k],     h0, c0);
                    c1 = fmaf(wB[k + 1], h1, c1);
                }
                const float ghA = a0 + a1;            // r (lanes 0-31) / z (lanes 32-63)
                const float ghB = c0 + c1;            // h_n (dup on halves)
                const float sA  = giA + ghA;
                const float zp  = __shfl_xor(sA, 32); // z-pre onto low lanes
                const float r   = sigm(sA);
                const float z   = sigm(zp);
                const float n   = tanh_fast(fmaf(r, ghB, giB));
                const float hn  = fmaf(z, v_h - n, n);   // (1-z)*n + z*h_prev
                v_h = hn;                                 // lanes 0-31 meaningful
                if (ln < HH) {
                    if (wv == 0)      h0s[cur][ln] = hn;
                    else if (wv == 1) h1s[cur][ln] = hn;
                    else              obuf[t & 31][ln] = hn;
                    if (t == TT - 1) out_hf[(size_t)(wv * BB + b) * HH + ln] = hn;
                }
            }
        } else if (wv < 6) {
            // ================= gi waves: feed-forward dots, one tick ahead ========
            const int l = wv - 3;
            const int t = tau - 3 - 2 * l;
            if (t >= 0 && t < TT) {
                const float vx = (l == 0) ? y3s[prv][lo]
                               : (l == 1) ? h0s[prv][lo]
                                          : h1s[prv][lo];
                float a0 = bA, a1 = 0.f, c0 = bB, c1 = 0.f;
                #pragma unroll
                for (int k = 0; k < 32; k += 2) {
                    const float x0 = rlane(vx, k), x1 = rlane(vx, k + 1);
                    a0 = fmaf(wA[k],     x0, a0);
                    a1 = fmaf(wA[k + 1], x1, a1);
                    c0 = fmaf(wB[k],     x0, c0);
                    c1 = fmaf(wB[k + 1], x1, c1);
                }
                gib[l][cur][ln] = a0 + a1;
                if (ln < 32) gib[l][cur][64 + ln] = c0 + c1;
            }
        } else if (wv == 6) {
            // ================= MLP y2(tau-1) then y1(tau) =========================
            float y2 = 0.f;
            const bool has2 = (tau >= 1) && (tau - 1 < TT);
            if (has2) {                                 // y2 from v_y1p (regs only)
                float a0 = bB, a1 = 0.f;
                #pragma unroll
                for (int k = 0; k < 32; k += 2) {
                    const float x0 = rlane(v_y1p, k), x1 = rlane(v_y1p, k + 1);
                    a0 = fmaf(wB[k],     x0, a0);
                    a1 = fmaf(wB[k + 1], x1, a1);
                }
                y2 = fmaxf(a0 + a1, 0.f);
            }
            if (tau < TT) {                             // y1 from ebuf
                const float ve = ebuf[(tau >> 6) & 1][tau & (CH - 1)][lo];
                float a0 = bA, a1 = 0.f;
                #pragma unroll
                for (int k = 0; k < 32; k += 2) {
                    const float e0 = rlane(ve, k), e1 = rlane(ve, k + 1);
                    a0 = fmaf(wA[k],     e0, a0);
                    a1 = fmaf(wA[k + 1], e1, a1);
                }
                v_y1p = fmaxf(a0 + a1, 0.f);
            }
            if (has2 && ln < HH) y2s[cur][ln] = y2;
        } else {
            // ================= wv7: y3(tau-2) + refill + flush ====================
            if ((tau & (CH - 1)) == 0) {                // emb refill (1/64 ticks)
                const int cn = (tau >> 6) + 1;
                if (cn < TT / CH) {
                    float4*       edst = reinterpret_cast<float4*>(&ebuf[cn & 1][0][0]);
                    const float4* esrc = reinterpret_cast<const float4*>(emb);
                    const int base = cn * CH;
                    #pragma unroll
                    for (int k = 0; k < 8; ++k) {
                        const int task = k * 64 + ln, row = task >> 3, q = task & 7;
                        edst[row * 8 + q] = esrc[(size_t)idxbuf[base + row] * 8 + q];
                    }
                }
            }
            const int t3 = tau - 2;
            if (t3 >= 0 && t3 < TT) {                   // y3 from y2s
                const float vx = y2s[prv][lo];
                float a0 = bA, a1 = 0.f;
                #pragma unroll
                for (int k = 0; k < 32; k += 2) {
                    const float x0 = rlane(vx, k), x1 = rlane(vx, k + 1);
                    a0 = fmaf(wA[k],     x0, a0);
                    a1 = fmaf(wA[k + 1], x1, a1);
                }
                const float y3 = fmaxf(a0 + a1, 0.f);
                if (ln < HH) y3s[cur][ln] = y3;
            }
            const int tl = tau - 9;                     // flush (1/16 ticks)
            if (tl >= 15 && (tl & 15) == 15) {
                const int tc0 = tl - 15;
                #pragma unroll
                for (int k = 0; k < 2; ++k) {
                    const int task = k * 64 + ln, row = task >> 3, q = task & 7;
                    const float4 v = *reinterpret_cast<const float4*>(&obuf[(tc0 + row) & 31][q * 4]);
                    *reinterpret_cast<float4*>(&out_seq[(size_t)(tc0 + row) * HH + q * 4]) = v;
                }
            }
        }
        __syncthreads();
    }
}

extern "C" void kernel_launch(void* const* d_in, const int* in_sizes, int n_in,
                              void* d_out, int out_size, void* d_ws, size_t ws_size,
                              hipStream_t stream) {
    const int*   x   = (const int*)  d_in[0];
    const float* hid = (const float*)d_in[1];
    const float* emb = (const float*)d_in[2];
    const float* W1  = (const float*)d_in[3];
    const float* b1  = (const float*)d_in[4];
    const float* W2  = (const float*)d_in[5];
    const float* b2  = (const float*)d_in[6];
    const float* W3  = (const float*)d_in[7];
    const float* b3  = (const float*)d_in[8];
    const float* Wih = (const float*)d_in[9];
    const float* Whh = (const float*)d_in[10];
    const float* bih = (const float*)d_in[11];
    const float* bhh = (const float*)d_in[12];

    rnn_fused<<<dim3(BB), dim3(NT), 0, stream>>>(
        x, hid, emb, W1, b1, W2, b2, W3, b3, Wih, Whh, bih, bhh, (float*)d_out);
}